// Round 1
// 1349.167 us; speedup vs baseline: 1.0983x; 1.0983x over previous
//
#include <hip/hip_runtime.h>

// ---------------------------------------------------------------------------
// RGAT: 3 edge types (writes: author->paper, cites: paper->paper,
// publishes: venue->paper), single-head GAT conv each, summed into paper out.
//
// R1 change vs baseline (1482us): replace atomic edge_scatter (WRITE_SIZE was
// E*256B = 10x write amplification through L2) + edge_score passes with an
// on-device counting sort by dst and a wave-per-dst gather that computes
// w=exp(lrelu(s_src+s_dst)), per-type denoms, and the normalized weighted sum
// entirely in registers -> out written exactly once per dst, zero out-atomics.
// edge_score / wbuf / denom / init_out all folded away.
// ---------------------------------------------------------------------------

#define F_IN 768
#define C_OUT 64
#define BN 80     // 64 h cols + 16 extra (score cols in 64..67)
#define TILE_M 64
#define BK 64
#define LDK 72    // padded LDS k-stride (bf16 elems): 144 B rows, 16B-aligned
#define EPS 1e-16f

typedef __bf16 bf16x8 __attribute__((ext_vector_type(8)));
typedef float  f32x4  __attribute__((ext_vector_type(4)));

// ---------------------------------------------------------------------------
// Build WextT[80][768] bf16 per node-type GEMM:
//   cols 0..63  = W_src (transposed)
//   col  64     = u = W_src @ a_src          (-> s_src)
//   cols 65..67 = v_* = W*_dst @ a*_dst      (paper GEMM only -> s_dst's)
//   rest zero
// ---------------------------------------------------------------------------
__global__ void prep_weights(
    const float* __restrict__ Ww_src, const float* __restrict__ aw_src,
    const float* __restrict__ Wc_src, const float* __restrict__ ac_src,
    const float* __restrict__ Wp_src, const float* __restrict__ ap_src,
    const float* __restrict__ Ww_dst, const float* __restrict__ aw_dst,
    const float* __restrict__ Wc_dst, const float* __restrict__ ac_dst,
    const float* __restrict__ Wp_dst, const float* __restrict__ ap_dst,
    __bf16* __restrict__ WTw, __bf16* __restrict__ WTc, __bf16* __restrict__ WTp)
{
    int type = blockIdx.x;  // 0=author GEMM(writes), 1=paper GEMM(cites), 2=venue GEMM(pub)
    const float* Ws = (type == 0) ? Ww_src : (type == 1) ? Wc_src : Wp_src;
    const float* as = (type == 0) ? aw_src : (type == 1) ? ac_src : ap_src;
    __bf16* WT = (type == 0) ? WTw : (type == 1) ? WTc : WTp;

    for (int r = threadIdx.x; r < F_IN; r += blockDim.x) {
        const float* wrow = Ws + (size_t)r * C_OUT;
        float u = 0.f;
        for (int c = 0; c < C_OUT; ++c) {
            float wv = wrow[c];
            WT[(size_t)c * F_IN + r] = (__bf16)wv;
            u += wv * as[c];
        }
        WT[(size_t)64 * F_IN + r] = (__bf16)u;
        for (int c = 65; c < BN; ++c) WT[(size_t)c * F_IN + r] = (__bf16)0.f;
        if (type == 1) {
            const float* r1 = Ww_dst + (size_t)r * C_OUT;
            const float* r2 = Wc_dst + (size_t)r * C_OUT;
            const float* r3 = Wp_dst + (size_t)r * C_OUT;
            float vw = 0.f, vc = 0.f, vp = 0.f;
            for (int c = 0; c < C_OUT; ++c) {
                vw += r1[c] * aw_dst[c];
                vc += r2[c] * ac_dst[c];
                vp += r3[c] * ap_dst[c];
            }
            WT[(size_t)65 * F_IN + r] = (__bf16)vw;
            WT[(size_t)66 * F_IN + r] = (__bf16)vc;
            WT[(size_t)67 * F_IN + r] = (__bf16)vp;
        }
    }
}

// ---------------------------------------------------------------------------
// Fused GEMM: H[M,64] = X[M,768] @ Wext (bf16 MFMA, fp32 acc)
// plus score columns 64..67 scattered to s0..s3 (null = unused).
// Block: 256 thr (4 waves), 64 rows x 80 cols, K-chunks of 64.
// ---------------------------------------------------------------------------
__global__ __launch_bounds__(256) void gemm_fused(
    const float* __restrict__ X, const __bf16* __restrict__ WT,
    float* __restrict__ H,
    float* __restrict__ s0, float* __restrict__ s1,
    float* __restrict__ s2, float* __restrict__ s3, int M)
{
    __shared__ __bf16 As[TILE_M][LDK];
    __shared__ __bf16 Bs[BN][LDK];

    const int tid  = threadIdx.x;
    const int lane = tid & 63;
    const int warp = tid >> 6;
    const int colq = lane & 15;
    const int quad = lane >> 4;
    const int rowBase = blockIdx.x * TILE_M;

    f32x4 acc[5];
#pragma unroll
    for (int t = 0; t < 5; ++t) acc[t] = (f32x4){0.f, 0.f, 0.f, 0.f};

    const int arow  = tid >> 2;          // 0..63
    const int akoff = (tid & 3) * 16;    // 0,16,32,48
    const int grow  = rowBase + arow;
    const bool rowOK = grow < M;
    const float* xrow = X + (size_t)grow * F_IN;

    for (int kc = 0; kc < F_IN; kc += BK) {
        // ---- stage A tile (fp32 -> bf16) ----
        f32x4 av[4];
        if (rowOK) {
            const f32x4* xp = (const f32x4*)(xrow + kc + akoff);
            av[0] = xp[0]; av[1] = xp[1]; av[2] = xp[2]; av[3] = xp[3];
        } else {
#pragma unroll
            for (int i = 0; i < 4; ++i) av[i] = (f32x4){0.f, 0.f, 0.f, 0.f};
        }
        bf16x8 cv[2];
#pragma unroll
        for (int i = 0; i < 4; ++i)
#pragma unroll
            for (int j = 0; j < 4; ++j)
                cv[i >> 1][(i & 1) * 4 + j] = (__bf16)av[i][j];
        *(bf16x8*)&As[arow][akoff]     = cv[0];
        *(bf16x8*)&As[arow][akoff + 8] = cv[1];

        // ---- stage B tile (already bf16, WextT is [80][768]) ----
        for (int c = tid; c < (BN * BK / 8); c += 256) {   // 640 chunks of 8 bf16
            int br = c >> 3, bo = (c & 7) * 8;
            *(bf16x8*)&Bs[br][bo] =
                *(const bf16x8*)&WT[(size_t)br * F_IN + kc + bo];
        }
        __syncthreads();

        // ---- MFMA ----
#pragma unroll
        for (int kk = 0; kk < BK; kk += 32) {
            bf16x8 a = *(const bf16x8*)&As[warp * 16 + colq][kk + quad * 8];
#pragma unroll
            for (int t = 0; t < 5; ++t) {
                bf16x8 b = *(const bf16x8*)&Bs[t * 16 + colq][kk + quad * 8];
                acc[t] = __builtin_amdgcn_mfma_f32_16x16x32_bf16(a, b, acc[t], 0, 0, 0);
            }
        }
        __syncthreads();
    }

    // ---- epilogue: C/D layout col=lane&15, row=quad*4+reg ----
    const int orow0 = rowBase + warp * 16 + quad * 4;
#pragma unroll
    for (int r = 0; r < 4; ++r) {
        int row = orow0 + r;
        if (row < M) {
#pragma unroll
            for (int t = 0; t < 4; ++t)
                H[(size_t)row * C_OUT + t * 16 + colq] = acc[t][r];
            if (colq < 4) {
                float* sp = (colq == 0) ? s0 : (colq == 1) ? s1 : (colq == 2) ? s2 : s3;
                if (sp) sp[row] = acc[4][r];
            }
        }
    }
}

// ---------------------------------------------------------------------------
// CSR build: histogram over dst of all 3 edge lists
// ---------------------------------------------------------------------------
__global__ void hist3(const int* __restrict__ d1, int E1,
                      const int* __restrict__ d2, int E2,
                      const int* __restrict__ d3, int E3,
                      int* __restrict__ cnt)
{
    int i0 = blockIdx.x * blockDim.x + threadIdx.x;
    int stride = gridDim.x * blockDim.x;
    for (int i = i0; i < E1; i += stride) atomicAdd(&cnt[d1[i]], 1);
    for (int i = i0; i < E2; i += stride) atomicAdd(&cnt[d2[i]], 1);
    for (int i = i0; i < E3; i += stride) atomicAdd(&cnt[d3[i]], 1);
}

// ---------------------------------------------------------------------------
// Exclusive scan of cnt[n] -> rowptr (3-phase: block-local, block sums, add).
// 1024 elements per block (256 thr x 4).
// ---------------------------------------------------------------------------
__global__ void scan1(const int* __restrict__ cnt, int n,
                      int* __restrict__ rowptr, int* __restrict__ bsums)
{
    __shared__ int sm[256];
    const int t = threadIdx.x;
    const int base = blockIdx.x * 1024 + t * 4;
    int v[4];
    int tot = 0;
#pragma unroll
    for (int k = 0; k < 4; ++k) {
        v[k] = (base + k < n) ? cnt[base + k] : 0;
        tot += v[k];
    }
    sm[t] = tot;
    __syncthreads();
    for (int off = 1; off < 256; off <<= 1) {
        int add = (t >= off) ? sm[t - off] : 0;
        __syncthreads();
        sm[t] += add;
        __syncthreads();
    }
    int run = sm[t] - tot;   // exclusive prefix for this thread's first elem
#pragma unroll
    for (int k = 0; k < 4; ++k) {
        if (base + k < n) rowptr[base + k] = run;
        run += v[k];
    }
    if (t == 255) bsums[blockIdx.x] = sm[255];
}

__global__ void scan2(int* __restrict__ bsums, int nb)
{
    __shared__ int sm[256];
    const int t = threadIdx.x;
    int v = (t < nb) ? bsums[t] : 0;
    sm[t] = v;
    __syncthreads();
    for (int off = 1; off < 256; off <<= 1) {
        int add = (t >= off) ? sm[t - off] : 0;
        __syncthreads();
        sm[t] += add;
        __syncthreads();
    }
    if (t < nb) bsums[t] = sm[t] - v;   // exclusive
}

__global__ void scan3(const int* __restrict__ bsums, int n, int Etot,
                      int* __restrict__ rowptr, int* __restrict__ cursor)
{
    int i = blockIdx.x * blockDim.x + threadIdx.x;
    if (i < n) {
        int r = rowptr[i] + bsums[i >> 10];
        rowptr[i] = r;
        cursor[i] = r;
    }
    if (i == 0) rowptr[n] = Etot;
}

// ---------------------------------------------------------------------------
// Counting-sort scatter: eidx[pos] = (type<<24) | src, grouped by dst.
// cursor atomics live in a 600KB L2-resident array; eidx (7.8MB) is L2-absorbed.
// ---------------------------------------------------------------------------
__global__ void edge_sort3(const int* __restrict__ s1, const int* __restrict__ d1, int E1,
                           const int* __restrict__ s2, const int* __restrict__ d2, int E2,
                           const int* __restrict__ s3, const int* __restrict__ d3, int E3,
                           int* __restrict__ cursor, unsigned* __restrict__ eidx)
{
    int i0 = blockIdx.x * blockDim.x + threadIdx.x;
    int stride = gridDim.x * blockDim.x;
    for (int i = i0; i < E1; i += stride) {
        int p = atomicAdd(&cursor[d1[i]], 1);
        eidx[p] = (0u << 24) | (unsigned)s1[i];
    }
    for (int i = i0; i < E2; i += stride) {
        int p = atomicAdd(&cursor[d2[i]], 1);
        eidx[p] = (1u << 24) | (unsigned)s2[i];
    }
    for (int i = i0; i < E3; i += stride) {
        int p = atomicAdd(&cursor[d3[i]], 1);
        eidx[p] = (2u << 24) | (unsigned)s3[i];
    }
}

// ---------------------------------------------------------------------------
// Wave-per-dst gather: for each dst paper, iterate its (sorted) incoming
// edges of all 3 types; compute w = exp(leaky_relu(s_src+s_dst)) lane-parallel,
// accumulate per-type denom + w*H[src] in registers, write out once.
// lane = output channel (64 == C_OUT). No atomics, no segment-max needed
// (|e| small, fp32-safe — same as validated baseline).
// ---------------------------------------------------------------------------
__global__ __launch_bounds__(256) void gat_gather(
    const unsigned* __restrict__ eidx, const int* __restrict__ rowptr,
    const float* __restrict__ Ha, const float* __restrict__ Hp, const float* __restrict__ Hv,
    const float* __restrict__ ssw, const float* __restrict__ ssc, const float* __restrict__ ssp,
    const float* __restrict__ sdw, const float* __restrict__ sdc, const float* __restrict__ sdp,
    const float* __restrict__ bw, const float* __restrict__ bc, const float* __restrict__ bp,
    float* __restrict__ out, int Nd)
{
    const int lane = threadIdx.x & 63;
    const int wid = (blockIdx.x * blockDim.x + threadIdx.x) >> 6;
    const int nw = (gridDim.x * blockDim.x) >> 6;
    const float bsum = bw[lane] + bc[lane] + bp[lane];

    for (int d = wid; d < Nd; d += nw) {
        const int start = rowptr[d];
        const int end   = rowptr[d + 1];
        const float sd0 = sdw[d], sd1 = sdc[d], sd2 = sdp[d];
        float a0 = 0.f, a1 = 0.f, a2 = 0.f;
        float dn0 = 0.f, dn1 = 0.f, dn2 = 0.f;

        for (int base = start; base < end; base += 64) {
            int n = end - base;
            if (n > 64) n = 64;
            // lane-parallel edge scoring for this chunk
            unsigned ew = 0u;
            float w = 0.f;
            if (lane < n) {
                ew = eidx[base + lane];
                int t = (int)(ew >> 24);
                int s = (int)(ew & 0xFFFFFFu);
                float ss = (t == 0) ? ssw[s] : (t == 1) ? ssc[s] : ssp[s];
                float sd = (t == 0) ? sd0 : (t == 1) ? sd1 : sd2;
                float e = ss + sd;
                e = (e >= 0.f) ? e : 0.2f * e;
                w = __expf(e);
                if (t == 0) dn0 += w; else if (t == 1) dn1 += w; else dn2 += w;
            }
            // broadcast each edge; coalesced 256B H-row load; 4-deep MLP
            int j = 0;
            for (; j + 4 <= n; j += 4) {
#pragma unroll
                for (int u = 0; u < 4; ++u) {
                    float wj = __shfl(w, j + u);
                    unsigned ej = (unsigned)__shfl((int)ew, j + u);
                    int tj = (int)(ej >> 24);
                    int sj = (int)(ej & 0xFFFFFFu);
                    const float* Hr = (tj == 0) ? Ha : (tj == 1) ? Hp : Hv;
                    float hv = Hr[(size_t)sj * C_OUT + lane];
                    if (tj == 0) a0 += wj * hv;
                    else if (tj == 1) a1 += wj * hv;
                    else a2 += wj * hv;
                }
            }
            for (; j < n; ++j) {
                float wj = __shfl(w, j);
                unsigned ej = (unsigned)__shfl((int)ew, j);
                int tj = (int)(ej >> 24);
                int sj = (int)(ej & 0xFFFFFFu);
                const float* Hr = (tj == 0) ? Ha : (tj == 1) ? Hp : Hv;
                float hv = Hr[(size_t)sj * C_OUT + lane];
                if (tj == 0) a0 += wj * hv;
                else if (tj == 1) a1 += wj * hv;
                else a2 += wj * hv;
            }
        }
        // wave-reduce per-type denominators (all lanes end with the total)
#pragma unroll
        for (int off = 32; off > 0; off >>= 1) {
            dn0 += __shfl_xor(dn0, off);
            dn1 += __shfl_xor(dn1, off);
            dn2 += __shfl_xor(dn2, off);
        }
        out[(size_t)d * C_OUT + lane] =
            a0 / (dn0 + EPS) + a1 / (dn1 + EPS) + a2 / (dn2 + EPS) + bsum;
    }
}

// ---------------------------------------------------------------------------
extern "C" void kernel_launch(void* const* d_in, const int* in_sizes, int n_in,
                              void* d_out, int out_size, void* d_ws, size_t ws_size,
                              hipStream_t stream)
{
    const float* x_a = (const float*)d_in[0];
    const float* x_p = (const float*)d_in[1];
    const float* x_v = (const float*)d_in[2];
    const int* w_src = (const int*)d_in[3];
    const int* w_dst = (const int*)d_in[4];
    const int* c_src = (const int*)d_in[5];
    const int* c_dst = (const int*)d_in[6];
    const int* p_src = (const int*)d_in[7];
    const int* p_dst = (const int*)d_in[8];
    const float* Ww_src = (const float*)d_in[9];
    const float* Ww_dst = (const float*)d_in[10];
    const float* aw_src = (const float*)d_in[11];
    const float* aw_dst = (const float*)d_in[12];
    const float* bw     = (const float*)d_in[13];
    const float* Wc_src = (const float*)d_in[14];
    const float* Wc_dst = (const float*)d_in[15];
    const float* ac_src = (const float*)d_in[16];
    const float* ac_dst = (const float*)d_in[17];
    const float* bc     = (const float*)d_in[18];
    const float* Wp_src = (const float*)d_in[19];
    const float* Wp_dst = (const float*)d_in[20];
    const float* ap_src = (const float*)d_in[21];
    const float* ap_dst = (const float*)d_in[22];
    const float* bp     = (const float*)d_in[23];
    float* out = (float*)d_out;

    const int Na = in_sizes[0] / F_IN;
    const int Np = in_sizes[1] / F_IN;
    const int Nv = in_sizes[2] / F_IN;
    const int Ew = in_sizes[3];
    const int Ec = in_sizes[5];
    const int Ep = in_sizes[7];
    const int Etot = Ew + Ec + Ep;

    // ---- workspace layout ----
    char* ws = (char*)d_ws;
    size_t off = 0;
    auto alloc = [&](size_t bytes) -> void* {
        off = (off + 255) & ~(size_t)255;
        void* p = ws + off;
        off += bytes;
        return p;
    };
    __bf16* WTw = (__bf16*)alloc((size_t)BN * F_IN * 2);
    __bf16* WTc = (__bf16*)alloc((size_t)BN * F_IN * 2);
    __bf16* WTp = (__bf16*)alloc((size_t)BN * F_IN * 2);
    float* Ha = (float*)alloc((size_t)Na * C_OUT * 4);
    float* Hp = (float*)alloc((size_t)Np * C_OUT * 4);
    float* Hv = (float*)alloc((size_t)Nv * C_OUT * 4);
    float* s_w_src = (float*)alloc((size_t)Na * 4);
    float* s_c_src = (float*)alloc((size_t)Np * 4);
    float* s_p_src = (float*)alloc((size_t)Nv * 4);
    float* s_w_dst = (float*)alloc((size_t)Np * 4);
    float* s_c_dst = (float*)alloc((size_t)Np * 4);
    float* s_p_dst = (float*)alloc((size_t)Np * 4);
    int* cnt    = (int*)alloc((size_t)Np * 4);
    int* rowptr = (int*)alloc((size_t)(Np + 1) * 4);
    int* cursor = (int*)alloc((size_t)Np * 4);
    int* bsums  = (int*)alloc(1024);
    unsigned* eidx = (unsigned*)alloc((size_t)Etot * 4);
    (void)ws_size; (void)n_in; (void)out_size;

    hipMemsetAsync(cnt, 0, (size_t)Np * 4, stream);

    prep_weights<<<3, 256, 0, stream>>>(
        Ww_src, aw_src, Wc_src, ac_src, Wp_src, ap_src,
        Ww_dst, aw_dst, Wc_dst, ac_dst, Wp_dst, ap_dst,
        WTw, WTc, WTp);

    gemm_fused<<<(Na + TILE_M - 1) / TILE_M, 256, 0, stream>>>(
        x_a, WTw, Ha, s_w_src, nullptr, nullptr, nullptr, Na);
    gemm_fused<<<(Np + TILE_M - 1) / TILE_M, 256, 0, stream>>>(
        x_p, WTc, Hp, s_c_src, s_w_dst, s_c_dst, s_p_dst, Np);
    gemm_fused<<<(Nv + TILE_M - 1) / TILE_M, 256, 0, stream>>>(
        x_v, WTp, Hv, s_p_src, nullptr, nullptr, nullptr, Nv);

    // ---- CSR build (counting sort by dst, all 3 types combined) ----
    hist3<<<1024, 256, 0, stream>>>(w_dst, Ew, c_dst, Ec, p_dst, Ep, cnt);
    const int NB = (Np + 1023) / 1024;   // <= 256 for Np <= 262144
    scan1<<<NB, 256, 0, stream>>>(cnt, Np, rowptr, bsums);
    scan2<<<1, 256, 0, stream>>>(bsums, NB);
    scan3<<<(Np + 255) / 256, 256, 0, stream>>>(bsums, Np, Etot, rowptr, cursor);
    edge_sort3<<<1024, 256, 0, stream>>>(
        w_src, w_dst, Ew, c_src, c_dst, Ec, p_src, p_dst, Ep, cursor, eidx);

    // ---- fused score+softmax+gather, one wave per dst paper ----
    gat_gather<<<2048, 256, 0, stream>>>(
        eidx, rowptr, Ha, Hp, Hv,
        s_w_src, s_c_src, s_p_src, s_w_dst, s_c_dst, s_p_dst,
        bw, bc, bp, out, Np);
}

// Round 2
// 1282.146 us; speedup vs baseline: 1.1557x; 1.0523x over previous
//
#include <hip/hip_runtime.h>

// ---------------------------------------------------------------------------
// RGAT: 3 edge types (writes: author->paper, cites: paper->paper,
// publishes: venue->paper), single-head GAT conv each, summed into paper out.
//
// R2 change vs R1 (1349us): gat_gather restructured from wave-per-dst
// (serial 1-load-per-step edge walk, 13/64 lanes active at avg degree 13)
// to 16-lane-group-per-dst: 4 dsts per wave, lane q holds channels [4q..4q+3]
// as f32x4, each edge row = 16 lanes x 16B = 256B coalesced. 4x memory-level
// parallelism, full lane utilization, group-local (4-step) denom reduce,
// f32x4 coalesced out store. Same math as R1 (absmax unchanged).
// ---------------------------------------------------------------------------

#define F_IN 768
#define C_OUT 64
#define BN 80     // 64 h cols + 16 extra (score cols in 64..67)
#define TILE_M 64
#define BK 64
#define LDK 72    // padded LDS k-stride (bf16 elems): 144 B rows, 16B-aligned
#define EPS 1e-16f

typedef __bf16 bf16x8 __attribute__((ext_vector_type(8)));
typedef float  f32x4  __attribute__((ext_vector_type(4)));

// ---------------------------------------------------------------------------
// Build WextT[80][768] bf16 per node-type GEMM:
//   cols 0..63  = W_src (transposed)
//   col  64     = u = W_src @ a_src          (-> s_src)
//   cols 65..67 = v_* = W*_dst @ a*_dst      (paper GEMM only -> s_dst's)
//   rest zero
// ---------------------------------------------------------------------------
__global__ void prep_weights(
    const float* __restrict__ Ww_src, const float* __restrict__ aw_src,
    const float* __restrict__ Wc_src, const float* __restrict__ ac_src,
    const float* __restrict__ Wp_src, const float* __restrict__ ap_src,
    const float* __restrict__ Ww_dst, const float* __restrict__ aw_dst,
    const float* __restrict__ Wc_dst, const float* __restrict__ ac_dst,
    const float* __restrict__ Wp_dst, const float* __restrict__ ap_dst,
    __bf16* __restrict__ WTw, __bf16* __restrict__ WTc, __bf16* __restrict__ WTp)
{
    int type = blockIdx.x;  // 0=author GEMM(writes), 1=paper GEMM(cites), 2=venue GEMM(pub)
    const float* Ws = (type == 0) ? Ww_src : (type == 1) ? Wc_src : Wp_src;
    const float* as = (type == 0) ? aw_src : (type == 1) ? ac_src : ap_src;
    __bf16* WT = (type == 0) ? WTw : (type == 1) ? WTc : WTp;

    for (int r = threadIdx.x; r < F_IN; r += blockDim.x) {
        const float* wrow = Ws + (size_t)r * C_OUT;
        float u = 0.f;
        for (int c = 0; c < C_OUT; ++c) {
            float wv = wrow[c];
            WT[(size_t)c * F_IN + r] = (__bf16)wv;
            u += wv * as[c];
        }
        WT[(size_t)64 * F_IN + r] = (__bf16)u;
        for (int c = 65; c < BN; ++c) WT[(size_t)c * F_IN + r] = (__bf16)0.f;
        if (type == 1) {
            const float* r1 = Ww_dst + (size_t)r * C_OUT;
            const float* r2 = Wc_dst + (size_t)r * C_OUT;
            const float* r3 = Wp_dst + (size_t)r * C_OUT;
            float vw = 0.f, vc = 0.f, vp = 0.f;
            for (int c = 0; c < C_OUT; ++c) {
                vw += r1[c] * aw_dst[c];
                vc += r2[c] * ac_dst[c];
                vp += r3[c] * ap_dst[c];
            }
            WT[(size_t)65 * F_IN + r] = (__bf16)vw;
            WT[(size_t)66 * F_IN + r] = (__bf16)vc;
            WT[(size_t)67 * F_IN + r] = (__bf16)vp;
        }
    }
}

// ---------------------------------------------------------------------------
// Fused GEMM: H[M,64] = X[M,768] @ Wext (bf16 MFMA, fp32 acc)
// plus score columns 64..67 scattered to s0..s3 (null = unused).
// Block: 256 thr (4 waves), 64 rows x 80 cols, K-chunks of 64.
// ---------------------------------------------------------------------------
__global__ __launch_bounds__(256) void gemm_fused(
    const float* __restrict__ X, const __bf16* __restrict__ WT,
    float* __restrict__ H,
    float* __restrict__ s0, float* __restrict__ s1,
    float* __restrict__ s2, float* __restrict__ s3, int M)
{
    __shared__ __bf16 As[TILE_M][LDK];
    __shared__ __bf16 Bs[BN][LDK];

    const int tid  = threadIdx.x;
    const int lane = tid & 63;
    const int warp = tid >> 6;
    const int colq = lane & 15;
    const int quad = lane >> 4;
    const int rowBase = blockIdx.x * TILE_M;

    f32x4 acc[5];
#pragma unroll
    for (int t = 0; t < 5; ++t) acc[t] = (f32x4){0.f, 0.f, 0.f, 0.f};

    const int arow  = tid >> 2;          // 0..63
    const int akoff = (tid & 3) * 16;    // 0,16,32,48
    const int grow  = rowBase + arow;
    const bool rowOK = grow < M;
    const float* xrow = X + (size_t)grow * F_IN;

    for (int kc = 0; kc < F_IN; kc += BK) {
        // ---- stage A tile (fp32 -> bf16) ----
        f32x4 av[4];
        if (rowOK) {
            const f32x4* xp = (const f32x4*)(xrow + kc + akoff);
            av[0] = xp[0]; av[1] = xp[1]; av[2] = xp[2]; av[3] = xp[3];
        } else {
#pragma unroll
            for (int i = 0; i < 4; ++i) av[i] = (f32x4){0.f, 0.f, 0.f, 0.f};
        }
        bf16x8 cv[2];
#pragma unroll
        for (int i = 0; i < 4; ++i)
#pragma unroll
            for (int j = 0; j < 4; ++j)
                cv[i >> 1][(i & 1) * 4 + j] = (__bf16)av[i][j];
        *(bf16x8*)&As[arow][akoff]     = cv[0];
        *(bf16x8*)&As[arow][akoff + 8] = cv[1];

        // ---- stage B tile (already bf16, WextT is [80][768]) ----
        for (int c = tid; c < (BN * BK / 8); c += 256) {   // 640 chunks of 8 bf16
            int br = c >> 3, bo = (c & 7) * 8;
            *(bf16x8*)&Bs[br][bo] =
                *(const bf16x8*)&WT[(size_t)br * F_IN + kc + bo];
        }
        __syncthreads();

        // ---- MFMA ----
#pragma unroll
        for (int kk = 0; kk < BK; kk += 32) {
            bf16x8 a = *(const bf16x8*)&As[warp * 16 + colq][kk + quad * 8];
#pragma unroll
            for (int t = 0; t < 5; ++t) {
                bf16x8 b = *(const bf16x8*)&Bs[t * 16 + colq][kk + quad * 8];
                acc[t] = __builtin_amdgcn_mfma_f32_16x16x32_bf16(a, b, acc[t], 0, 0, 0);
            }
        }
        __syncthreads();
    }

    // ---- epilogue: C/D layout col=lane&15, row=quad*4+reg ----
    const int orow0 = rowBase + warp * 16 + quad * 4;
#pragma unroll
    for (int r = 0; r < 4; ++r) {
        int row = orow0 + r;
        if (row < M) {
#pragma unroll
            for (int t = 0; t < 4; ++t)
                H[(size_t)row * C_OUT + t * 16 + colq] = acc[t][r];
            if (colq < 4) {
                float* sp = (colq == 0) ? s0 : (colq == 1) ? s1 : (colq == 2) ? s2 : s3;
                if (sp) sp[row] = acc[4][r];
            }
        }
    }
}

// ---------------------------------------------------------------------------
// CSR build: histogram over dst of all 3 edge lists
// ---------------------------------------------------------------------------
__global__ void hist3(const int* __restrict__ d1, int E1,
                      const int* __restrict__ d2, int E2,
                      const int* __restrict__ d3, int E3,
                      int* __restrict__ cnt)
{
    int i0 = blockIdx.x * blockDim.x + threadIdx.x;
    int stride = gridDim.x * blockDim.x;
    for (int i = i0; i < E1; i += stride) atomicAdd(&cnt[d1[i]], 1);
    for (int i = i0; i < E2; i += stride) atomicAdd(&cnt[d2[i]], 1);
    for (int i = i0; i < E3; i += stride) atomicAdd(&cnt[d3[i]], 1);
}

// ---------------------------------------------------------------------------
// Exclusive scan of cnt[n] -> rowptr (3-phase: block-local, block sums, add).
// 1024 elements per block (256 thr x 4).
// ---------------------------------------------------------------------------
__global__ void scan1(const int* __restrict__ cnt, int n,
                      int* __restrict__ rowptr, int* __restrict__ bsums)
{
    __shared__ int sm[256];
    const int t = threadIdx.x;
    const int base = blockIdx.x * 1024 + t * 4;
    int v[4];
    int tot = 0;
#pragma unroll
    for (int k = 0; k < 4; ++k) {
        v[k] = (base + k < n) ? cnt[base + k] : 0;
        tot += v[k];
    }
    sm[t] = tot;
    __syncthreads();
    for (int off = 1; off < 256; off <<= 1) {
        int add = (t >= off) ? sm[t - off] : 0;
        __syncthreads();
        sm[t] += add;
        __syncthreads();
    }
    int run = sm[t] - tot;   // exclusive prefix for this thread's first elem
#pragma unroll
    for (int k = 0; k < 4; ++k) {
        if (base + k < n) rowptr[base + k] = run;
        run += v[k];
    }
    if (t == 255) bsums[blockIdx.x] = sm[255];
}

__global__ void scan2(int* __restrict__ bsums, int nb)
{
    __shared__ int sm[256];
    const int t = threadIdx.x;
    int v = (t < nb) ? bsums[t] : 0;
    sm[t] = v;
    __syncthreads();
    for (int off = 1; off < 256; off <<= 1) {
        int add = (t >= off) ? sm[t - off] : 0;
        __syncthreads();
        sm[t] += add;
        __syncthreads();
    }
    if (t < nb) bsums[t] = sm[t] - v;   // exclusive
}

__global__ void scan3(const int* __restrict__ bsums, int n, int Etot,
                      int* __restrict__ rowptr, int* __restrict__ cursor)
{
    int i = blockIdx.x * blockDim.x + threadIdx.x;
    if (i < n) {
        int r = rowptr[i] + bsums[i >> 10];
        rowptr[i] = r;
        cursor[i] = r;
    }
    if (i == 0) rowptr[n] = Etot;
}

// ---------------------------------------------------------------------------
// Counting-sort scatter: eidx[pos] = (type<<24) | src, grouped by dst.
// cursor atomics live in a 600KB L2-resident array; eidx (7.8MB) is L2-absorbed.
// ---------------------------------------------------------------------------
__global__ void edge_sort3(const int* __restrict__ s1, const int* __restrict__ d1, int E1,
                           const int* __restrict__ s2, const int* __restrict__ d2, int E2,
                           const int* __restrict__ s3, const int* __restrict__ d3, int E3,
                           int* __restrict__ cursor, unsigned* __restrict__ eidx)
{
    int i0 = blockIdx.x * blockDim.x + threadIdx.x;
    int stride = gridDim.x * blockDim.x;
    for (int i = i0; i < E1; i += stride) {
        int p = atomicAdd(&cursor[d1[i]], 1);
        eidx[p] = (0u << 24) | (unsigned)s1[i];
    }
    for (int i = i0; i < E2; i += stride) {
        int p = atomicAdd(&cursor[d2[i]], 1);
        eidx[p] = (1u << 24) | (unsigned)s2[i];
    }
    for (int i = i0; i < E3; i += stride) {
        int p = atomicAdd(&cursor[d3[i]], 1);
        eidx[p] = (2u << 24) | (unsigned)s3[i];
    }
}

// ---------------------------------------------------------------------------
// 16-lane-group-per-dst gather: 4 dsts per wave. Lane q (=lane&15) of a group
// holds output channels [4q..4q+3] as f32x4. Per edge: 16 lanes x 16B = 256B
// coalesced H-row load; 4 groups give 4 loads in flight per wave per step.
// Scoring is group-parallel (16 edges/step, avg degree 13 -> one step).
// Denom reduce = 4 shfl_xor within the group. out stored once, f32x4/lane.
// No atomics, no segment-max (|e| small, fp32-safe — validated in R0/R1).
// ---------------------------------------------------------------------------
__global__ __launch_bounds__(256) void gat_gather(
    const unsigned* __restrict__ eidx, const int* __restrict__ rowptr,
    const float* __restrict__ Ha, const float* __restrict__ Hp, const float* __restrict__ Hv,
    const float* __restrict__ ssw, const float* __restrict__ ssc, const float* __restrict__ ssp,
    const float* __restrict__ sdw, const float* __restrict__ sdc, const float* __restrict__ sdp,
    const float* __restrict__ bw, const float* __restrict__ bc, const float* __restrict__ bp,
    float* __restrict__ out, int Nd)
{
    const int lane = threadIdx.x & 63;
    const int q    = lane & 15;          // channel quad within group
    const int gbase = lane & ~15;        // first lane of my 16-lane group
    const int gid  = (blockIdx.x * blockDim.x + threadIdx.x) >> 4;  // global group
    const int ng   = (gridDim.x * blockDim.x) >> 4;

    const f32x4* Ha4 = (const f32x4*)Ha;
    const f32x4* Hp4 = (const f32x4*)Hp;
    const f32x4* Hv4 = (const f32x4*)Hv;
    f32x4* out4 = (f32x4*)out;

    // combined bias for my channel quad
    const f32x4 b4 = ((const f32x4*)bw)[q] + ((const f32x4*)bc)[q] + ((const f32x4*)bp)[q];

    for (int d = gid; d < Nd; d += ng) {
        const int start = rowptr[d];
        const int end   = rowptr[d + 1];
        const float sd0 = sdw[d], sd1 = sdc[d], sd2 = sdp[d];
        f32x4 a0 = (f32x4){0.f,0.f,0.f,0.f};
        f32x4 a1 = (f32x4){0.f,0.f,0.f,0.f};
        f32x4 a2 = (f32x4){0.f,0.f,0.f,0.f};
        float dn0 = 0.f, dn1 = 0.f, dn2 = 0.f;

        for (int base = start; base < end; base += 16) {
            int n = end - base;
            if (n > 16) n = 16;
            // group-parallel edge scoring for this chunk
            unsigned ew = 0u;
            float w = 0.f;
            if (q < n) {
                ew = eidx[base + q];
                int t = (int)(ew >> 24);
                int s = (int)(ew & 0xFFFFFFu);
                float ss = (t == 0) ? ssw[s] : (t == 1) ? ssc[s] : ssp[s];
                float sd = (t == 0) ? sd0 : (t == 1) ? sd1 : sd2;
                float e = ss + sd;
                e = (e >= 0.f) ? e : 0.2f * e;
                w = __expf(e);
                if (t == 0) dn0 += w; else if (t == 1) dn1 += w; else dn2 += w;
            }
            // per-edge broadcast within group; f32x4 coalesced H-row loads
            int j = 0;
            for (; j + 2 <= n; j += 2) {
#pragma unroll
                for (int u = 0; u < 2; ++u) {
                    float wj = __shfl(w, gbase + j + u);
                    unsigned ej = (unsigned)__shfl((int)ew, gbase + j + u);
                    int tj = (int)(ej >> 24);
                    int sj = (int)(ej & 0xFFFFFFu);
                    const f32x4* Hr = (tj == 0) ? Ha4 : (tj == 1) ? Hp4 : Hv4;
                    f32x4 hv = Hr[(size_t)sj * 16 + q];
                    if (tj == 0) a0 += wj * hv;
                    else if (tj == 1) a1 += wj * hv;
                    else a2 += wj * hv;
                }
            }
            for (; j < n; ++j) {
                float wj = __shfl(w, gbase + j);
                unsigned ej = (unsigned)__shfl((int)ew, gbase + j);
                int tj = (int)(ej >> 24);
                int sj = (int)(ej & 0xFFFFFFu);
                const f32x4* Hr = (tj == 0) ? Ha4 : (tj == 1) ? Hp4 : Hv4;
                f32x4 hv = Hr[(size_t)sj * 16 + q];
                if (tj == 0) a0 += wj * hv;
                else if (tj == 1) a1 += wj * hv;
                else a2 += wj * hv;
            }
        }
        // group-local reduce of per-type denominators (offsets 1,2,4,8 stay in group)
#pragma unroll
        for (int off = 8; off > 0; off >>= 1) {
            dn0 += __shfl_xor(dn0, off);
            dn1 += __shfl_xor(dn1, off);
            dn2 += __shfl_xor(dn2, off);
        }
        f32x4 res = a0 / (dn0 + EPS) + a1 / (dn1 + EPS) + a2 / (dn2 + EPS) + b4;
        out4[(size_t)d * 16 + q] = res;
    }
}

// ---------------------------------------------------------------------------
extern "C" void kernel_launch(void* const* d_in, const int* in_sizes, int n_in,
                              void* d_out, int out_size, void* d_ws, size_t ws_size,
                              hipStream_t stream)
{
    const float* x_a = (const float*)d_in[0];
    const float* x_p = (const float*)d_in[1];
    const float* x_v = (const float*)d_in[2];
    const int* w_src = (const int*)d_in[3];
    const int* w_dst = (const int*)d_in[4];
    const int* c_src = (const int*)d_in[5];
    const int* c_dst = (const int*)d_in[6];
    const int* p_src = (const int*)d_in[7];
    const int* p_dst = (const int*)d_in[8];
    const float* Ww_src = (const float*)d_in[9];
    const float* Ww_dst = (const float*)d_in[10];
    const float* aw_src = (const float*)d_in[11];
    const float* aw_dst = (const float*)d_in[12];
    const float* bw     = (const float*)d_in[13];
    const float* Wc_src = (const float*)d_in[14];
    const float* Wc_dst = (const float*)d_in[15];
    const float* ac_src = (const float*)d_in[16];
    const float* ac_dst = (const float*)d_in[17];
    const float* bc     = (const float*)d_in[18];
    const float* Wp_src = (const float*)d_in[19];
    const float* Wp_dst = (const float*)d_in[20];
    const float* ap_src = (const float*)d_in[21];
    const float* ap_dst = (const float*)d_in[22];
    const float* bp     = (const float*)d_in[23];
    float* out = (float*)d_out;

    const int Na = in_sizes[0] / F_IN;
    const int Np = in_sizes[1] / F_IN;
    const int Nv = in_sizes[2] / F_IN;
    const int Ew = in_sizes[3];
    const int Ec = in_sizes[5];
    const int Ep = in_sizes[7];
    const int Etot = Ew + Ec + Ep;

    // ---- workspace layout ----
    char* ws = (char*)d_ws;
    size_t off = 0;
    auto alloc = [&](size_t bytes) -> void* {
        off = (off + 255) & ~(size_t)255;
        void* p = ws + off;
        off += bytes;
        return p;
    };
    __bf16* WTw = (__bf16*)alloc((size_t)BN * F_IN * 2);
    __bf16* WTc = (__bf16*)alloc((size_t)BN * F_IN * 2);
    __bf16* WTp = (__bf16*)alloc((size_t)BN * F_IN * 2);
    float* Ha = (float*)alloc((size_t)Na * C_OUT * 4);
    float* Hp = (float*)alloc((size_t)Np * C_OUT * 4);
    float* Hv = (float*)alloc((size_t)Nv * C_OUT * 4);
    float* s_w_src = (float*)alloc((size_t)Na * 4);
    float* s_c_src = (float*)alloc((size_t)Np * 4);
    float* s_p_src = (float*)alloc((size_t)Nv * 4);
    float* s_w_dst = (float*)alloc((size_t)Np * 4);
    float* s_c_dst = (float*)alloc((size_t)Np * 4);
    float* s_p_dst = (float*)alloc((size_t)Np * 4);
    int* cnt    = (int*)alloc((size_t)Np * 4);
    int* rowptr = (int*)alloc((size_t)(Np + 1) * 4);
    int* cursor = (int*)alloc((size_t)Np * 4);
    int* bsums  = (int*)alloc(1024);
    unsigned* eidx = (unsigned*)alloc((size_t)Etot * 4);
    (void)ws_size; (void)n_in; (void)out_size;

    hipMemsetAsync(cnt, 0, (size_t)Np * 4, stream);

    prep_weights<<<3, 256, 0, stream>>>(
        Ww_src, aw_src, Wc_src, ac_src, Wp_src, ap_src,
        Ww_dst, aw_dst, Wc_dst, ac_dst, Wp_dst, ap_dst,
        WTw, WTc, WTp);

    gemm_fused<<<(Na + TILE_M - 1) / TILE_M, 256, 0, stream>>>(
        x_a, WTw, Ha, s_w_src, nullptr, nullptr, nullptr, Na);
    gemm_fused<<<(Np + TILE_M - 1) / TILE_M, 256, 0, stream>>>(
        x_p, WTc, Hp, s_c_src, s_w_dst, s_c_dst, s_p_dst, Np);
    gemm_fused<<<(Nv + TILE_M - 1) / TILE_M, 256, 0, stream>>>(
        x_v, WTp, Hv, s_p_src, nullptr, nullptr, nullptr, Nv);

    // ---- CSR build (counting sort by dst, all 3 types combined) ----
    hist3<<<1024, 256, 0, stream>>>(w_dst, Ew, c_dst, Ec, p_dst, Ep, cnt);
    const int NB = (Np + 1023) / 1024;   // <= 256 for Np <= 262144
    scan1<<<NB, 256, 0, stream>>>(cnt, Np, rowptr, bsums);
    scan2<<<1, 256, 0, stream>>>(bsums, NB);
    scan3<<<(Np + 255) / 256, 256, 0, stream>>>(bsums, Np, Etot, rowptr, cursor);
    edge_sort3<<<1024, 256, 0, stream>>>(
        w_src, w_dst, Ew, c_src, c_dst, Ec, p_src, p_dst, Ep, cursor, eidx);

    // ---- fused score+softmax+gather, 16-lane group per dst paper ----
    gat_gather<<<2048, 256, 0, stream>>>(
        eidx, rowptr, Ha, Hp, Hv,
        s_w_src, s_c_src, s_p_src, s_w_dst, s_c_dst, s_p_dst,
        bw, bc, bp, out, Np);
}

// Round 3
// 1277.279 us; speedup vs baseline: 1.1601x; 1.0038x over previous
//
#include <hip/hip_runtime.h>

// ---------------------------------------------------------------------------
// RGAT: 3 edge types (writes: author->paper, cites: paper->paper,
// publishes: venue->paper), single-head GAT conv each, summed into paper out.
//
// R3 changes vs R2 (1282us):
//  (a) GEMM rewritten LDS-free: A-fragments load direct from X (rows are
//      warp-private, no reuse), B-fragments stream from L2 (Wext is 120KB,
//      shared by ALL blocks; total B traffic ~31MB). Deletes all barriers,
//      all staging VALU, A's LDS round-trip. Fragment math identical to the
//      verified R2 kernel -> same absmax.
//  (b) Counting sort is now type-major within dst (key = 3*dst+type), so the
//      gather inner loop is branch-free per segment: fixed H base, fixed
//      accumulator, 2 shfl + 1 f32x4 load + 4 FMA per edge.
//  (c) Fusions: prep_weights+hist in one launch; 3 GEMMs + edge_sort in one
//      launch (HBM/MFMA-bound GEMM overlaps atomic-bound sort). 11->7 launches.
// ---------------------------------------------------------------------------

#define F_IN 768
#define C_OUT 64
#define BN 80     // 64 h cols + 16 extra (score cols in 64..67)
#define TILE_M 64
#define BK 64
#define EPS 1e-16f

typedef __bf16 bf16x8 __attribute__((ext_vector_type(8)));
typedef float  f32x4  __attribute__((ext_vector_type(4)));

// ---------------------------------------------------------------------------
// Build WextT[80][768] bf16 per node-type GEMM (blocks 0..2) + dst-type-major
// degree histogram (blocks 3..). cnt must be pre-zeroed.
//   WextT cols 0..63 = W_src^T, col 64 = W_src@a_src, cols 65..67 (paper only)
//   = W*_dst@a*_dst, rest zero.
// ---------------------------------------------------------------------------
__global__ void prep_hist(
    const float* __restrict__ Ww_src, const float* __restrict__ aw_src,
    const float* __restrict__ Wc_src, const float* __restrict__ ac_src,
    const float* __restrict__ Wp_src, const float* __restrict__ ap_src,
    const float* __restrict__ Ww_dst, const float* __restrict__ aw_dst,
    const float* __restrict__ Wc_dst, const float* __restrict__ ac_dst,
    const float* __restrict__ Wp_dst, const float* __restrict__ ap_dst,
    __bf16* __restrict__ WTw, __bf16* __restrict__ WTc, __bf16* __restrict__ WTp,
    const int* __restrict__ d1, int E1,
    const int* __restrict__ d2, int E2,
    const int* __restrict__ d3, int E3,
    int* __restrict__ cnt)
{
    if (blockIdx.x < 3) {
        int type = blockIdx.x;
        const float* Ws = (type == 0) ? Ww_src : (type == 1) ? Wc_src : Wp_src;
        const float* as = (type == 0) ? aw_src : (type == 1) ? ac_src : ap_src;
        __bf16* WT = (type == 0) ? WTw : (type == 1) ? WTc : WTp;

        for (int r = threadIdx.x; r < F_IN; r += blockDim.x) {
            const float* wrow = Ws + (size_t)r * C_OUT;
            float u = 0.f;
            for (int c = 0; c < C_OUT; ++c) {
                float wv = wrow[c];
                WT[(size_t)c * F_IN + r] = (__bf16)wv;
                u += wv * as[c];
            }
            WT[(size_t)64 * F_IN + r] = (__bf16)u;
            for (int c = 65; c < BN; ++c) WT[(size_t)c * F_IN + r] = (__bf16)0.f;
            if (type == 1) {
                const float* r1 = Ww_dst + (size_t)r * C_OUT;
                const float* r2 = Wc_dst + (size_t)r * C_OUT;
                const float* r3 = Wp_dst + (size_t)r * C_OUT;
                float vw = 0.f, vc = 0.f, vp = 0.f;
                for (int c = 0; c < C_OUT; ++c) {
                    vw += r1[c] * aw_dst[c];
                    vc += r2[c] * ac_dst[c];
                    vp += r3[c] * ap_dst[c];
                }
                WT[(size_t)65 * F_IN + r] = (__bf16)vw;
                WT[(size_t)66 * F_IN + r] = (__bf16)vc;
                WT[(size_t)67 * F_IN + r] = (__bf16)vp;
            }
        }
        return;
    }
    int i0 = (blockIdx.x - 3) * blockDim.x + threadIdx.x;
    int stride = (gridDim.x - 3) * blockDim.x;
    for (int i = i0; i < E1; i += stride) atomicAdd(&cnt[3 * d1[i] + 0], 1);
    for (int i = i0; i < E2; i += stride) atomicAdd(&cnt[3 * d2[i] + 1], 1);
    for (int i = i0; i < E3; i += stride) atomicAdd(&cnt[3 * d3[i] + 2], 1);
}

// ---------------------------------------------------------------------------
// Exclusive scan of cnt[n] -> rowptr (+cursor copy): 2048 elems/block.
// ---------------------------------------------------------------------------
__global__ void scan1(const int* __restrict__ cnt, int n,
                      int* __restrict__ rowptr, int* __restrict__ bsums)
{
    __shared__ int sm[256];
    const int t = threadIdx.x;
    const int base = blockIdx.x * 2048 + t * 8;
    int v[8];
    int tot = 0;
#pragma unroll
    for (int k = 0; k < 8; ++k) {
        v[k] = (base + k < n) ? cnt[base + k] : 0;
        tot += v[k];
    }
    sm[t] = tot;
    __syncthreads();
    for (int off = 1; off < 256; off <<= 1) {
        int add = (t >= off) ? sm[t - off] : 0;
        __syncthreads();
        sm[t] += add;
        __syncthreads();
    }
    int run = sm[t] - tot;
#pragma unroll
    for (int k = 0; k < 8; ++k) {
        if (base + k < n) rowptr[base + k] = run;
        run += v[k];
    }
    if (t == 255) bsums[blockIdx.x] = sm[255];
}

__global__ void scan2(int* __restrict__ bsums, int nb)
{
    __shared__ int sm[256];
    const int t = threadIdx.x;
    int v = (t < nb) ? bsums[t] : 0;
    sm[t] = v;
    __syncthreads();
    for (int off = 1; off < 256; off <<= 1) {
        int add = (t >= off) ? sm[t - off] : 0;
        __syncthreads();
        sm[t] += add;
        __syncthreads();
    }
    if (t < nb) bsums[t] = sm[t] - v;   // exclusive
}

__global__ void scan3(const int* __restrict__ bsums, int n, int Etot,
                      int* __restrict__ rowptr, int* __restrict__ cursor)
{
    int i = blockIdx.x * blockDim.x + threadIdx.x;
    if (i < n) {
        int r = rowptr[i] + bsums[i >> 11];
        rowptr[i] = r;
        cursor[i] = r;
    }
    if (i == 0) rowptr[n] = Etot;
}

// ---------------------------------------------------------------------------
// Mega-kernel: blocks [0, BA+BP+BV) = LDS-free fused GEMM (3 node types),
// blocks after = counting-sort scatter (eidx[pos]=src, key 3*dst+type).
//
// GEMM: H[M,64] = X[M,768] @ Wext, bf16 MFMA fp32 acc, + score cols 64..67.
// Per wave: rows warp*16+colq are private -> A direct global->reg (fp32->bf16
// cvt in reg); B-frags direct from WT (L2-hot, 120KB shared by all blocks).
// No LDS, no barriers. A prefetched one K-chunk ahead.
// ---------------------------------------------------------------------------
__global__ __launch_bounds__(256) void gemm_sort(
    const float* __restrict__ xa, const float* __restrict__ xp, const float* __restrict__ xv,
    const __bf16* __restrict__ WTw, const __bf16* __restrict__ WTc, const __bf16* __restrict__ WTp,
    float* __restrict__ Ha, float* __restrict__ Hp, float* __restrict__ Hv,
    float* __restrict__ ssw, float* __restrict__ ssc, float* __restrict__ ssp,
    float* __restrict__ sdw, float* __restrict__ sdc, float* __restrict__ sdp,
    int Na, int Np, int Nv, int BA, int BP, int BV,
    const int* __restrict__ ws_, const int* __restrict__ wd_, int Ew,
    const int* __restrict__ cs_, const int* __restrict__ cd_, int Ec,
    const int* __restrict__ ps_, const int* __restrict__ pd_, int Ep,
    int* __restrict__ cursor, unsigned* __restrict__ eidx)
{
    const int bid = blockIdx.x;
    const int tid = threadIdx.x;
    const int NG = BA + BP + BV;

    if (bid >= NG) {
        // ---- counting-sort scatter path ----
        int i0 = (bid - NG) * blockDim.x + tid;
        int stride = (gridDim.x - NG) * blockDim.x;
        for (int i = i0; i < Ew; i += stride) {
            int p = atomicAdd(&cursor[3 * wd_[i] + 0], 1);
            eidx[p] = (unsigned)ws_[i];
        }
        for (int i = i0; i < Ec; i += stride) {
            int p = atomicAdd(&cursor[3 * cd_[i] + 1], 1);
            eidx[p] = (unsigned)cs_[i];
        }
        for (int i = i0; i < Ep; i += stride) {
            int p = atomicAdd(&cursor[3 * pd_[i] + 2], 1);
            eidx[p] = (unsigned)ps_[i];
        }
        return;
    }

    // ---- GEMM path ----
    const float* X; const __bf16* WT; float* H;
    float *s0, *s1, *s2, *s3; int M, rb;
    if (bid < BA)           { X = xa; WT = WTw; H = Ha; s0 = ssw; s1 = s2 = s3 = nullptr; M = Na; rb = bid; }
    else if (bid < BA + BP) { X = xp; WT = WTc; H = Hp; s0 = ssc; s1 = sdw; s2 = sdc; s3 = sdp; M = Np; rb = bid - BA; }
    else                    { X = xv; WT = WTp; H = Hv; s0 = ssp; s1 = s2 = s3 = nullptr; M = Nv; rb = bid - BA - BP; }

    const int lane = tid & 63;
    const int warp = tid >> 6;
    const int colq = lane & 15;
    const int quad = lane >> 4;
    const int rowBase = rb * TILE_M;
    const int grow = rowBase + warp * 16 + colq;
    const bool rowOK = grow < M;
    const float* xrow = X + (size_t)grow * F_IN + quad * 8;
    const __bf16* wrow = WT + (size_t)colq * F_IN + quad * 8;   // + t*16*F_IN + kc (+32)

    f32x4 acc[5];
#pragma unroll
    for (int t = 0; t < 5; ++t) acc[t] = (f32x4){0.f, 0.f, 0.f, 0.f};

    // A prefetch pipeline (one K-chunk ahead)
    f32x4 x0{}, x1{}, x2{}, x3{};
    if (rowOK) {
        x0 = *(const f32x4*)(xrow);
        x1 = *(const f32x4*)(xrow + 4);
        x2 = *(const f32x4*)(xrow + 32);
        x3 = *(const f32x4*)(xrow + 36);
    }

    for (int ci = 0; ci < F_IN / BK; ++ci) {
        const int kc = ci * BK;
        // issue next chunk's A loads (HBM) before compute
        f32x4 n0{}, n1{}, n2{}, n3{};
        if (rowOK && ci + 1 < F_IN / BK) {
            const float* xn = xrow + kc + BK;
            n0 = *(const f32x4*)(xn);
            n1 = *(const f32x4*)(xn + 4);
            n2 = *(const f32x4*)(xn + 32);
            n3 = *(const f32x4*)(xn + 36);
        }
        // convert current A to bf16 fragments
        bf16x8 av0, av1;
#pragma unroll
        for (int j = 0; j < 4; ++j) {
            av0[j] = (__bf16)x0[j]; av0[4 + j] = (__bf16)x1[j];
            av1[j] = (__bf16)x2[j]; av1[4 + j] = (__bf16)x3[j];
        }
        // B fragments direct from L2; MFMA
        const __bf16* wp = wrow + kc;
#pragma unroll
        for (int t = 0; t < 5; ++t) {
            bf16x8 b = *(const bf16x8*)(wp + (size_t)t * 16 * F_IN);
            acc[t] = __builtin_amdgcn_mfma_f32_16x16x32_bf16(av0, b, acc[t], 0, 0, 0);
        }
#pragma unroll
        for (int t = 0; t < 5; ++t) {
            bf16x8 b = *(const bf16x8*)(wp + (size_t)t * 16 * F_IN + 32);
            acc[t] = __builtin_amdgcn_mfma_f32_16x16x32_bf16(av1, b, acc[t], 0, 0, 0);
        }
        x0 = n0; x1 = n1; x2 = n2; x3 = n3;
    }

    // ---- epilogue: C/D layout col=lane&15, row=quad*4+reg ----
    const int orow0 = rowBase + warp * 16 + quad * 4;
#pragma unroll
    for (int r = 0; r < 4; ++r) {
        int row = orow0 + r;
        if (row < M) {
#pragma unroll
            for (int t = 0; t < 4; ++t)
                H[(size_t)row * C_OUT + t * 16 + colq] = acc[t][r];
            if (colq < 4) {
                float* sp = (colq == 0) ? s0 : (colq == 1) ? s1 : (colq == 2) ? s2 : s3;
                if (sp) sp[row] = acc[4][r];
            }
        }
    }
}

// ---------------------------------------------------------------------------
// Per-(dst,type) segment gather: branch-free inner loop (fixed H base, fixed
// score array). Returns sum(w_i * H[src_i]) / (sum w_i + EPS) for the segment.
// ---------------------------------------------------------------------------
static __device__ __forceinline__ f32x4 segsum(
    const unsigned* __restrict__ eidx, int beg, int end,
    const float* __restrict__ ss, float sd,
    const f32x4* __restrict__ H4, int q, int gbase)
{
    f32x4 at = (f32x4){0.f, 0.f, 0.f, 0.f};
    float dn = 0.f;
    for (int base = beg; base < end; base += 16) {
        int n = end - base;
        if (n > 16) n = 16;
        float w = 0.f;
        int s = 0;
        if (q < n) {
            s = (int)eidx[base + q];
            float e = ss[s] + sd;
            e = (e >= 0.f) ? e : 0.2f * e;
            w = __expf(e);
            dn += w;
        }
        int j = 0;
        for (; j + 4 <= n; j += 4) {
#pragma unroll
            for (int u = 0; u < 4; ++u) {
                float wj = __shfl(w, gbase + j + u);
                int sj = __shfl(s, gbase + j + u);
                at += wj * H4[(size_t)sj * 16 + q];
            }
        }
        for (; j < n; ++j) {
            float wj = __shfl(w, gbase + j);
            int sj = __shfl(s, gbase + j);
            at += wj * H4[(size_t)sj * 16 + q];
        }
    }
#pragma unroll
    for (int off = 8; off > 0; off >>= 1) dn += __shfl_xor(dn, off);
    return at / (dn + EPS);
}

// ---------------------------------------------------------------------------
// 16-lane-group-per-dst gather, type-major segments. Lane q holds channels
// [4q..4q+3] as f32x4; per edge 16 lanes x 16B = 256B coalesced H-row load.
// No atomics, no segment-max (|e| small, fp32-safe — validated R0-R2).
// ---------------------------------------------------------------------------
__global__ __launch_bounds__(256) void gat_gather(
    const unsigned* __restrict__ eidx, const int* __restrict__ rowptr,
    const float* __restrict__ Ha, const float* __restrict__ Hp, const float* __restrict__ Hv,
    const float* __restrict__ ssw, const float* __restrict__ ssc, const float* __restrict__ ssp,
    const float* __restrict__ sdw, const float* __restrict__ sdc, const float* __restrict__ sdp,
    const float* __restrict__ bw, const float* __restrict__ bc, const float* __restrict__ bp,
    float* __restrict__ out, int Nd)
{
    const int lane = threadIdx.x & 63;
    const int q    = lane & 15;
    const int gbase = lane & ~15;
    const int gid  = (blockIdx.x * blockDim.x + threadIdx.x) >> 4;
    const int ng   = (gridDim.x * blockDim.x) >> 4;

    const f32x4* Ha4 = (const f32x4*)Ha;
    const f32x4* Hp4 = (const f32x4*)Hp;
    const f32x4* Hv4 = (const f32x4*)Hv;
    f32x4* out4 = (f32x4*)out;

    const f32x4 b4 = ((const f32x4*)bw)[q] + ((const f32x4*)bc)[q] + ((const f32x4*)bp)[q];

    for (int d = gid; d < Nd; d += ng) {
        const int r0 = rowptr[3 * d];
        const int r1 = rowptr[3 * d + 1];
        const int r2 = rowptr[3 * d + 2];
        const int r3 = rowptr[3 * d + 3];
        f32x4 res = b4;
        res += segsum(eidx, r0, r1, ssw, sdw[d], Ha4, q, gbase);
        res += segsum(eidx, r1, r2, ssc, sdc[d], Hp4, q, gbase);
        res += segsum(eidx, r2, r3, ssp, sdp[d], Hv4, q, gbase);
        out4[(size_t)d * 16 + q] = res;
    }
}

// ---------------------------------------------------------------------------
extern "C" void kernel_launch(void* const* d_in, const int* in_sizes, int n_in,
                              void* d_out, int out_size, void* d_ws, size_t ws_size,
                              hipStream_t stream)
{
    const float* x_a = (const float*)d_in[0];
    const float* x_p = (const float*)d_in[1];
    const float* x_v = (const float*)d_in[2];
    const int* w_src = (const int*)d_in[3];
    const int* w_dst = (const int*)d_in[4];
    const int* c_src = (const int*)d_in[5];
    const int* c_dst = (const int*)d_in[6];
    const int* p_src = (const int*)d_in[7];
    const int* p_dst = (const int*)d_in[8];
    const float* Ww_src = (const float*)d_in[9];
    const float* Ww_dst = (const float*)d_in[10];
    const float* aw_src = (const float*)d_in[11];
    const float* aw_dst = (const float*)d_in[12];
    const float* bw     = (const float*)d_in[13];
    const float* Wc_src = (const float*)d_in[14];
    const float* Wc_dst = (const float*)d_in[15];
    const float* ac_src = (const float*)d_in[16];
    const float* ac_dst = (const float*)d_in[17];
    const float* bc     = (const float*)d_in[18];
    const float* Wp_src = (const float*)d_in[19];
    const float* Wp_dst = (const float*)d_in[20];
    const float* ap_src = (const float*)d_in[21];
    const float* ap_dst = (const float*)d_in[22];
    const float* bp     = (const float*)d_in[23];
    float* out = (float*)d_out;

    const int Na = in_sizes[0] / F_IN;
    const int Np = in_sizes[1] / F_IN;
    const int Nv = in_sizes[2] / F_IN;
    const int Ew = in_sizes[3];
    const int Ec = in_sizes[5];
    const int Ep = in_sizes[7];
    const int Etot = Ew + Ec + Ep;
    const int NSEG = 3 * Np;

    // ---- workspace layout ----
    char* ws = (char*)d_ws;
    size_t off = 0;
    auto alloc = [&](size_t bytes) -> void* {
        off = (off + 255) & ~(size_t)255;
        void* p = ws + off;
        off += bytes;
        return p;
    };
    __bf16* WTw = (__bf16*)alloc((size_t)BN * F_IN * 2);
    __bf16* WTc = (__bf16*)alloc((size_t)BN * F_IN * 2);
    __bf16* WTp = (__bf16*)alloc((size_t)BN * F_IN * 2);
    float* Ha = (float*)alloc((size_t)Na * C_OUT * 4);
    float* Hp = (float*)alloc((size_t)Np * C_OUT * 4);
    float* Hv = (float*)alloc((size_t)Nv * C_OUT * 4);
    float* s_w_src = (float*)alloc((size_t)Na * 4);
    float* s_c_src = (float*)alloc((size_t)Np * 4);
    float* s_p_src = (float*)alloc((size_t)Nv * 4);
    float* s_w_dst = (float*)alloc((size_t)Np * 4);
    float* s_c_dst = (float*)alloc((size_t)Np * 4);
    float* s_p_dst = (float*)alloc((size_t)Np * 4);
    int* cnt    = (int*)alloc((size_t)NSEG * 4);
    int* rowptr = (int*)alloc((size_t)(NSEG + 1) * 4);
    int* cursor = (int*)alloc((size_t)NSEG * 4);
    int* bsums  = (int*)alloc(1024);
    unsigned* eidx = (unsigned*)alloc((size_t)Etot * 4);
    (void)ws_size; (void)n_in; (void)out_size;

    hipMemsetAsync(cnt, 0, (size_t)NSEG * 4, stream);

    // prep weights (blocks 0-2) + dst-type histogram (blocks 3..)
    prep_hist<<<3 + 1024, 256, 0, stream>>>(
        Ww_src, aw_src, Wc_src, ac_src, Wp_src, ap_src,
        Ww_dst, aw_dst, Wc_dst, ac_dst, Wp_dst, ap_dst,
        WTw, WTc, WTp,
        w_dst, Ew, c_dst, Ec, p_dst, Ep, cnt);

    // exclusive scan over 3*Np (dst,type) counters
    const int NB = (NSEG + 2047) / 2048;    // <= 256 for Np <= 174762
    scan1<<<NB, 256, 0, stream>>>(cnt, NSEG, rowptr, bsums);
    scan2<<<1, 256, 0, stream>>>(bsums, NB);
    scan3<<<(NSEG + 255) / 256, 256, 0, stream>>>(bsums, NSEG, Etot, rowptr, cursor);

    // fused: 3 GEMMs (LDS-free, direct-A + L2-streamed-B) + counting-sort
    const int BA = (Na + TILE_M - 1) / TILE_M;
    const int BP = (Np + TILE_M - 1) / TILE_M;
    const int BV = (Nv + TILE_M - 1) / TILE_M;
    gemm_sort<<<BA + BP + BV + 1024, 256, 0, stream>>>(
        x_a, x_p, x_v, WTw, WTc, WTp, Ha, Hp, Hv,
        s_w_src, s_c_src, s_p_src, s_w_dst, s_c_dst, s_p_dst,
        Na, Np, Nv, BA, BP, BV,
        w_src, w_dst, Ew, c_src, c_dst, Ec, p_src, p_dst, Ep,
        cursor, eidx);

    // fused score+softmax+gather, 16-lane group per dst, type-major segments
    gat_gather<<<2048, 256, 0, stream>>>(
        eidx, rowptr, Ha, Hp, Hv,
        s_w_src, s_c_src, s_p_src, s_w_dst, s_c_dst, s_p_dst,
        bw, bc, bp, out, Np);
}

// Round 4
// 1250.417 us; speedup vs baseline: 1.1850x; 1.0215x over previous
//
#include <hip/hip_runtime.h>

// ---------------------------------------------------------------------------
// RGAT: 3 edge types (writes: author->paper, cites: paper->paper,
// publishes: venue->paper), single-head GAT conv each, summed into paper out.
//
// R4 changes vs R3 (1277us):
//  (a) Counting sort's 2nd atomic pass ELIMINATED. The histogram atomicAdd
//      already returns each edge's rank within its (dst,type) segment; we
//      persist rank[] (coalesced 4B writes) and placement becomes
//      pos = rowptr[key] + rank -> pure reads + one scattered write, zero
//      atomics, fully pipelined. (R3's fused sort phase was ~280us of
//      return-value-atomic latency chains with every pipe idle.)
//  (b) Place blocks are FIRST in the fused grid (before GEMM blocks) so the
//      latency-bound placement co-resides with the HBM/MFMA-bound GEMM
//      instead of trailing it (blocks dispatch roughly in order).
//  Same math, same intra-segment reassociation class -> absmax unchanged.
// ---------------------------------------------------------------------------

#define F_IN 768
#define C_OUT 64
#define BN 80     // 64 h cols + 16 extra (score cols in 64..67)
#define TILE_M 64
#define BK 64
#define EPS 1e-16f

typedef __bf16 bf16x8 __attribute__((ext_vector_type(8)));
typedef float  f32x4  __attribute__((ext_vector_type(4)));

// ---------------------------------------------------------------------------
// Blocks 0..2: build WextT[80][768] bf16 per node-type GEMM.
// Blocks 3.. : dst-type-major degree histogram; atomicAdd's return value is
//              the edge's rank within its (dst,type) segment -> rank arrays.
// cnt must be pre-zeroed.
// ---------------------------------------------------------------------------
__global__ void prep_hist(
    const float* __restrict__ Ww_src, const float* __restrict__ aw_src,
    const float* __restrict__ Wc_src, const float* __restrict__ ac_src,
    const float* __restrict__ Wp_src, const float* __restrict__ ap_src,
    const float* __restrict__ Ww_dst, const float* __restrict__ aw_dst,
    const float* __restrict__ Wc_dst, const float* __restrict__ ac_dst,
    const float* __restrict__ Wp_dst, const float* __restrict__ ap_dst,
    __bf16* __restrict__ WTw, __bf16* __restrict__ WTc, __bf16* __restrict__ WTp,
    const int* __restrict__ d1, int E1,
    const int* __restrict__ d2, int E2,
    const int* __restrict__ d3, int E3,
    int* __restrict__ cnt,
    int* __restrict__ rk1, int* __restrict__ rk2, int* __restrict__ rk3)
{
    if (blockIdx.x < 3) {
        int type = blockIdx.x;
        const float* Ws = (type == 0) ? Ww_src : (type == 1) ? Wc_src : Wp_src;
        const float* as = (type == 0) ? aw_src : (type == 1) ? ac_src : ap_src;
        __bf16* WT = (type == 0) ? WTw : (type == 1) ? WTc : WTp;

        for (int r = threadIdx.x; r < F_IN; r += blockDim.x) {
            const float* wrow = Ws + (size_t)r * C_OUT;
            float u = 0.f;
            for (int c = 0; c < C_OUT; ++c) {
                float wv = wrow[c];
                WT[(size_t)c * F_IN + r] = (__bf16)wv;
                u += wv * as[c];
            }
            WT[(size_t)64 * F_IN + r] = (__bf16)u;
            for (int c = 65; c < BN; ++c) WT[(size_t)c * F_IN + r] = (__bf16)0.f;
            if (type == 1) {
                const float* r1 = Ww_dst + (size_t)r * C_OUT;
                const float* r2 = Wc_dst + (size_t)r * C_OUT;
                const float* r3 = Wp_dst + (size_t)r * C_OUT;
                float vw = 0.f, vc = 0.f, vp = 0.f;
                for (int c = 0; c < C_OUT; ++c) {
                    vw += r1[c] * aw_dst[c];
                    vc += r2[c] * ac_dst[c];
                    vp += r3[c] * ap_dst[c];
                }
                WT[(size_t)65 * F_IN + r] = (__bf16)vw;
                WT[(size_t)66 * F_IN + r] = (__bf16)vc;
                WT[(size_t)67 * F_IN + r] = (__bf16)vp;
            }
        }
        return;
    }
    int i0 = (blockIdx.x - 3) * blockDim.x + threadIdx.x;
    int stride = (gridDim.x - 3) * blockDim.x;
    for (int i = i0; i < E1; i += stride) rk1[i] = atomicAdd(&cnt[3 * d1[i] + 0], 1);
    for (int i = i0; i < E2; i += stride) rk2[i] = atomicAdd(&cnt[3 * d2[i] + 1], 1);
    for (int i = i0; i < E3; i += stride) rk3[i] = atomicAdd(&cnt[3 * d3[i] + 2], 1);
}

// ---------------------------------------------------------------------------
// Exclusive scan of cnt[n] -> rowptr: 2048 elems/block.
// ---------------------------------------------------------------------------
__global__ void scan1(const int* __restrict__ cnt, int n,
                      int* __restrict__ rowptr, int* __restrict__ bsums)
{
    __shared__ int sm[256];
    const int t = threadIdx.x;
    const int base = blockIdx.x * 2048 + t * 8;
    int v[8];
    int tot = 0;
#pragma unroll
    for (int k = 0; k < 8; ++k) {
        v[k] = (base + k < n) ? cnt[base + k] : 0;
        tot += v[k];
    }
    sm[t] = tot;
    __syncthreads();
    for (int off = 1; off < 256; off <<= 1) {
        int add = (t >= off) ? sm[t - off] : 0;
        __syncthreads();
        sm[t] += add;
        __syncthreads();
    }
    int run = sm[t] - tot;
#pragma unroll
    for (int k = 0; k < 8; ++k) {
        if (base + k < n) rowptr[base + k] = run;
        run += v[k];
    }
    if (t == 255) bsums[blockIdx.x] = sm[255];
}

__global__ void scan2(int* __restrict__ bsums, int nb)
{
    __shared__ int sm[256];
    const int t = threadIdx.x;
    int v = (t < nb) ? bsums[t] : 0;
    sm[t] = v;
    __syncthreads();
    for (int off = 1; off < 256; off <<= 1) {
        int add = (t >= off) ? sm[t - off] : 0;
        __syncthreads();
        sm[t] += add;
        __syncthreads();
    }
    if (t < nb) bsums[t] = sm[t] - v;   // exclusive
}

__global__ void scan3(const int* __restrict__ bsums, int n, int Etot,
                      int* __restrict__ rowptr)
{
    int i = blockIdx.x * blockDim.x + threadIdx.x;
    if (i < n) rowptr[i] += bsums[i >> 11];
    if (i == 0) rowptr[n] = Etot;
}

// ---------------------------------------------------------------------------
// Mega-kernel: blocks [0, NPLACE) = atomic-free edge placement
// (eidx[rowptr[3*dst+type] + rank] = src), blocks [NPLACE, NPLACE+BA+BP+BV)
// = LDS-free fused GEMM (3 node types). Place blocks first so their
// latency-bound work co-resides with the GEMM blocks.
//
// GEMM: H[M,64] = X[M,768] @ Wext, bf16 MFMA fp32 acc, + score cols 64..67.
// Rows warp-private -> A direct global->reg (fp32->bf16 cvt in reg);
// B-frags direct from WT (L2-hot). No LDS, no barriers, A 1-chunk prefetch.
// ---------------------------------------------------------------------------
__global__ __launch_bounds__(256) void gemm_place(
    const float* __restrict__ xa, const float* __restrict__ xp, const float* __restrict__ xv,
    const __bf16* __restrict__ WTw, const __bf16* __restrict__ WTc, const __bf16* __restrict__ WTp,
    float* __restrict__ Ha, float* __restrict__ Hp, float* __restrict__ Hv,
    float* __restrict__ ssw, float* __restrict__ ssc, float* __restrict__ ssp,
    float* __restrict__ sdw, float* __restrict__ sdc, float* __restrict__ sdp,
    int Na, int Np, int Nv, int NPLACE, int BA, int BP, int BV,
    const int* __restrict__ ws_, const int* __restrict__ wd_, const int* __restrict__ rw_, int Ew,
    const int* __restrict__ cs_, const int* __restrict__ cd_, const int* __restrict__ rc_, int Ec,
    const int* __restrict__ ps_, const int* __restrict__ pd_, const int* __restrict__ rp_, int Ep,
    const int* __restrict__ rowptr, unsigned* __restrict__ eidx)
{
    const int bid = blockIdx.x;
    const int tid = threadIdx.x;

    if (bid < NPLACE) {
        // ---- atomic-free placement path ----
        int i0 = bid * blockDim.x + tid;
        int stride = NPLACE * blockDim.x;
        for (int i = i0; i < Ew; i += stride)
            eidx[rowptr[3 * wd_[i] + 0] + rw_[i]] = (unsigned)ws_[i];
        for (int i = i0; i < Ec; i += stride)
            eidx[rowptr[3 * cd_[i] + 1] + rc_[i]] = (unsigned)cs_[i];
        for (int i = i0; i < Ep; i += stride)
            eidx[rowptr[3 * pd_[i] + 2] + rp_[i]] = (unsigned)ps_[i];
        return;
    }

    // ---- GEMM path ----
    const int gb = bid - NPLACE;
    const float* X; const __bf16* WT; float* H;
    float *s0, *s1, *s2, *s3; int M, rb;
    if (gb < BA)           { X = xa; WT = WTw; H = Ha; s0 = ssw; s1 = s2 = s3 = nullptr; M = Na; rb = gb; }
    else if (gb < BA + BP) { X = xp; WT = WTc; H = Hp; s0 = ssc; s1 = sdw; s2 = sdc; s3 = sdp; M = Np; rb = gb - BA; }
    else                   { X = xv; WT = WTp; H = Hv; s0 = ssp; s1 = s2 = s3 = nullptr; M = Nv; rb = gb - BA - BP; }

    const int lane = tid & 63;
    const int warp = tid >> 6;
    const int colq = lane & 15;
    const int quad = lane >> 4;
    const int rowBase = rb * TILE_M;
    const int grow = rowBase + warp * 16 + colq;
    const bool rowOK = grow < M;
    const float* xrow = X + (size_t)grow * F_IN + quad * 8;
    const __bf16* wrow = WT + (size_t)colq * F_IN + quad * 8;

    f32x4 acc[5];
#pragma unroll
    for (int t = 0; t < 5; ++t) acc[t] = (f32x4){0.f, 0.f, 0.f, 0.f};

    f32x4 x0{}, x1{}, x2{}, x3{};
    if (rowOK) {
        x0 = *(const f32x4*)(xrow);
        x1 = *(const f32x4*)(xrow + 4);
        x2 = *(const f32x4*)(xrow + 32);
        x3 = *(const f32x4*)(xrow + 36);
    }

    for (int ci = 0; ci < F_IN / BK; ++ci) {
        const int kc = ci * BK;
        f32x4 n0{}, n1{}, n2{}, n3{};
        if (rowOK && ci + 1 < F_IN / BK) {
            const float* xn = xrow + kc + BK;
            n0 = *(const f32x4*)(xn);
            n1 = *(const f32x4*)(xn + 4);
            n2 = *(const f32x4*)(xn + 32);
            n3 = *(const f32x4*)(xn + 36);
        }
        bf16x8 av0, av1;
#pragma unroll
        for (int j = 0; j < 4; ++j) {
            av0[j] = (__bf16)x0[j]; av0[4 + j] = (__bf16)x1[j];
            av1[j] = (__bf16)x2[j]; av1[4 + j] = (__bf16)x3[j];
        }
        const __bf16* wp = wrow + kc;
#pragma unroll
        for (int t = 0; t < 5; ++t) {
            bf16x8 b = *(const bf16x8*)(wp + (size_t)t * 16 * F_IN);
            acc[t] = __builtin_amdgcn_mfma_f32_16x16x32_bf16(av0, b, acc[t], 0, 0, 0);
        }
#pragma unroll
        for (int t = 0; t < 5; ++t) {
            bf16x8 b = *(const bf16x8*)(wp + (size_t)t * 16 * F_IN + 32);
            acc[t] = __builtin_amdgcn_mfma_f32_16x16x32_bf16(av1, b, acc[t], 0, 0, 0);
        }
        x0 = n0; x1 = n1; x2 = n2; x3 = n3;
    }

    // ---- epilogue: C/D layout col=lane&15, row=quad*4+reg ----
    const int orow0 = rowBase + warp * 16 + quad * 4;
#pragma unroll
    for (int r = 0; r < 4; ++r) {
        int row = orow0 + r;
        if (row < M) {
#pragma unroll
            for (int t = 0; t < 4; ++t)
                H[(size_t)row * C_OUT + t * 16 + colq] = acc[t][r];
            if (colq < 4) {
                float* sp = (colq == 0) ? s0 : (colq == 1) ? s1 : (colq == 2) ? s2 : s3;
                if (sp) sp[row] = acc[4][r];
            }
        }
    }
}

// ---------------------------------------------------------------------------
// Per-(dst,type) segment gather: branch-free inner loop (fixed H base, fixed
// score array). Returns sum(w_i * H[src_i]) / (sum w_i + EPS) for the segment.
// ---------------------------------------------------------------------------
static __device__ __forceinline__ f32x4 segsum(
    const unsigned* __restrict__ eidx, int beg, int end,
    const float* __restrict__ ss, float sd,
    const f32x4* __restrict__ H4, int q, int gbase)
{
    f32x4 at = (f32x4){0.f, 0.f, 0.f, 0.f};
    float dn = 0.f;
    for (int base = beg; base < end; base += 16) {
        int n = end - base;
        if (n > 16) n = 16;
        float w = 0.f;
        int s = 0;
        if (q < n) {
            s = (int)eidx[base + q];
            float e = ss[s] + sd;
            e = (e >= 0.f) ? e : 0.2f * e;
            w = __expf(e);
            dn += w;
        }
        int j = 0;
        for (; j + 4 <= n; j += 4) {
#pragma unroll
            for (int u = 0; u < 4; ++u) {
                float wj = __shfl(w, gbase + j + u);
                int sj = __shfl(s, gbase + j + u);
                at += wj * H4[(size_t)sj * 16 + q];
            }
        }
        for (; j < n; ++j) {
            float wj = __shfl(w, gbase + j);
            int sj = __shfl(s, gbase + j);
            at += wj * H4[(size_t)sj * 16 + q];
        }
    }
#pragma unroll
    for (int off = 8; off > 0; off >>= 1) dn += __shfl_xor(dn, off);
    return at / (dn + EPS);
}

// ---------------------------------------------------------------------------
// 16-lane-group-per-dst gather, type-major segments. Lane q holds channels
// [4q..4q+3] as f32x4; per edge 16 lanes x 16B = 256B coalesced H-row load.
// No atomics, no segment-max (|e| small, fp32-safe — validated R0-R3).
// ---------------------------------------------------------------------------
__global__ __launch_bounds__(256) void gat_gather(
    const unsigned* __restrict__ eidx, const int* __restrict__ rowptr,
    const float* __restrict__ Ha, const float* __restrict__ Hp, const float* __restrict__ Hv,
    const float* __restrict__ ssw, const float* __restrict__ ssc, const float* __restrict__ ssp,
    const float* __restrict__ sdw, const float* __restrict__ sdc, const float* __restrict__ sdp,
    const float* __restrict__ bw, const float* __restrict__ bc, const float* __restrict__ bp,
    float* __restrict__ out, int Nd)
{
    const int lane = threadIdx.x & 63;
    const int q    = lane & 15;
    const int gbase = lane & ~15;
    const int gid  = (blockIdx.x * blockDim.x + threadIdx.x) >> 4;
    const int ng   = (gridDim.x * blockDim.x) >> 4;

    const f32x4* Ha4 = (const f32x4*)Ha;
    const f32x4* Hp4 = (const f32x4*)Hp;
    const f32x4* Hv4 = (const f32x4*)Hv;
    f32x4* out4 = (f32x4*)out;

    const f32x4 b4 = ((const f32x4*)bw)[q] + ((const f32x4*)bc)[q] + ((const f32x4*)bp)[q];

    for (int d = gid; d < Nd; d += ng) {
        const int r0 = rowptr[3 * d];
        const int r1 = rowptr[3 * d + 1];
        const int r2 = rowptr[3 * d + 2];
        const int r3 = rowptr[3 * d + 3];
        f32x4 res = b4;
        res += segsum(eidx, r0, r1, ssw, sdw[d], Ha4, q, gbase);
        res += segsum(eidx, r1, r2, ssc, sdc[d], Hp4, q, gbase);
        res += segsum(eidx, r2, r3, ssp, sdp[d], Hv4, q, gbase);
        out4[(size_t)d * 16 + q] = res;
    }
}

// ---------------------------------------------------------------------------
extern "C" void kernel_launch(void* const* d_in, const int* in_sizes, int n_in,
                              void* d_out, int out_size, void* d_ws, size_t ws_size,
                              hipStream_t stream)
{
    const float* x_a = (const float*)d_in[0];
    const float* x_p = (const float*)d_in[1];
    const float* x_v = (const float*)d_in[2];
    const int* w_src = (const int*)d_in[3];
    const int* w_dst = (const int*)d_in[4];
    const int* c_src = (const int*)d_in[5];
    const int* c_dst = (const int*)d_in[6];
    const int* p_src = (const int*)d_in[7];
    const int* p_dst = (const int*)d_in[8];
    const float* Ww_src = (const float*)d_in[9];
    const float* Ww_dst = (const float*)d_in[10];
    const float* aw_src = (const float*)d_in[11];
    const float* aw_dst = (const float*)d_in[12];
    const float* bw     = (const float*)d_in[13];
    const float* Wc_src = (const float*)d_in[14];
    const float* Wc_dst = (const float*)d_in[15];
    const float* ac_src = (const float*)d_in[16];
    const float* ac_dst = (const float*)d_in[17];
    const float* bc     = (const float*)d_in[18];
    const float* Wp_src = (const float*)d_in[19];
    const float* Wp_dst = (const float*)d_in[20];
    const float* ap_src = (const float*)d_in[21];
    const float* ap_dst = (const float*)d_in[22];
    const float* bp     = (const float*)d_in[23];
    float* out = (float*)d_out;

    const int Na = in_sizes[0] / F_IN;
    const int Np = in_sizes[1] / F_IN;
    const int Nv = in_sizes[2] / F_IN;
    const int Ew = in_sizes[3];
    const int Ec = in_sizes[5];
    const int Ep = in_sizes[7];
    const int Etot = Ew + Ec + Ep;
    const int NSEG = 3 * Np;

    // ---- workspace layout ----
    char* ws = (char*)d_ws;
    size_t off = 0;
    auto alloc = [&](size_t bytes) -> void* {
        off = (off + 255) & ~(size_t)255;
        void* p = ws + off;
        off += bytes;
        return p;
    };
    __bf16* WTw = (__bf16*)alloc((size_t)BN * F_IN * 2);
    __bf16* WTc = (__bf16*)alloc((size_t)BN * F_IN * 2);
    __bf16* WTp = (__bf16*)alloc((size_t)BN * F_IN * 2);
    float* Ha = (float*)alloc((size_t)Na * C_OUT * 4);
    float* Hp = (float*)alloc((size_t)Np * C_OUT * 4);
    float* Hv = (float*)alloc((size_t)Nv * C_OUT * 4);
    float* s_w_src = (float*)alloc((size_t)Na * 4);
    float* s_c_src = (float*)alloc((size_t)Np * 4);
    float* s_p_src = (float*)alloc((size_t)Nv * 4);
    float* s_w_dst = (float*)alloc((size_t)Np * 4);
    float* s_c_dst = (float*)alloc((size_t)Np * 4);
    float* s_p_dst = (float*)alloc((size_t)Np * 4);
    int* cnt    = (int*)alloc((size_t)NSEG * 4);
    int* rowptr = (int*)alloc((size_t)(NSEG + 1) * 4);
    int* bsums  = (int*)alloc(1024);
    int* rk_w   = (int*)alloc((size_t)Ew * 4);
    int* rk_c   = (int*)alloc((size_t)Ec * 4);
    int* rk_p   = (int*)alloc((size_t)Ep * 4);
    unsigned* eidx = (unsigned*)alloc((size_t)Etot * 4);
    (void)ws_size; (void)n_in; (void)out_size;

    hipMemsetAsync(cnt, 0, (size_t)NSEG * 4, stream);

    // prep weights (blocks 0-2) + dst-type histogram with rank capture
    prep_hist<<<3 + 1024, 256, 0, stream>>>(
        Ww_src, aw_src, Wc_src, ac_src, Wp_src, ap_src,
        Ww_dst, aw_dst, Wc_dst, ac_dst, Wp_dst, ap_dst,
        WTw, WTc, WTp,
        w_dst, Ew, c_dst, Ec, p_dst, Ep, cnt,
        rk_w, rk_c, rk_p);

    // exclusive scan over 3*Np (dst,type) counters
    const int NB = (NSEG + 2047) / 2048;    // <= 256 for Np <= 174762
    scan1<<<NB, 256, 0, stream>>>(cnt, NSEG, rowptr, bsums);
    scan2<<<1, 256, 0, stream>>>(bsums, NB);
    scan3<<<(NSEG + 255) / 256, 256, 0, stream>>>(bsums, NSEG, Etot, rowptr);

    // fused: atomic-free placement (first) + 3 LDS-free GEMMs
    const int BA = (Na + TILE_M - 1) / TILE_M;
    const int BP = (Np + TILE_M - 1) / TILE_M;
    const int BV = (Nv + TILE_M - 1) / TILE_M;
    const int NPLACE = 1024;
    gemm_place<<<NPLACE + BA + BP + BV, 256, 0, stream>>>(
        x_a, x_p, x_v, WTw, WTc, WTp, Ha, Hp, Hv,
        s_w_src, s_c_src, s_p_src, s_w_dst, s_c_dst, s_p_dst,
        Na, Np, Nv, NPLACE, BA, BP, BV,
        w_src, w_dst, rk_w, Ew,
        c_src, c_dst, rk_c, Ec,
        p_src, p_dst, rk_p, Ep,
        rowptr, eidx);

    // fused score+softmax+gather, 16-lane group per dst, type-major segments
    gat_gather<<<2048, 256, 0, stream>>>(
        eidx, rowptr, Ha, Hp, Hv,
        s_w_src, s_c_src, s_p_src, s_w_dst, s_c_dst, s_p_dst,
        bw, bc, bp, out, Np);
}